// Round 10
// baseline (236.344 us; speedup 1.0000x reference)
//
#include <hip/hip_runtime.h>

typedef _Float16 f16;
typedef f16 f16x8 __attribute__((ext_vector_type(8)));
typedef __fp16 h16x2 __attribute__((ext_vector_type(2)));   // cvt_pkrtz native type
typedef float f32x4 __attribute__((ext_vector_type(4)));
typedef float f32x2 __attribute__((ext_vector_type(2)));

#define MFMA16(A, B, C) __builtin_amdgcn_mfma_f32_16x16x32_f16((A), (B), (C), 0, 0, 0)
#define LGKM_DRAIN() asm volatile("s_waitcnt lgkmcnt(0)" ::: "memory")

__device__ __forceinline__ float E2(float x) {   // 2^x
#if __has_builtin(__builtin_amdgcn_exp2f)
  return __builtin_amdgcn_exp2f(x);
#else
  return __expf(x * 0.69314718056f);
#endif
}

__device__ __forceinline__ f16x8 cvt8(float4 a, float4 b) {
  union { h16x2 h[4]; f16x8 v; } u;
  u.h[0] = __builtin_amdgcn_cvt_pkrtz(a.x, a.y);
  u.h[1] = __builtin_amdgcn_cvt_pkrtz(a.z, a.w);
  u.h[2] = __builtin_amdgcn_cvt_pkrtz(b.x, b.y);
  u.h[3] = __builtin_amdgcn_cvt_pkrtz(b.z, b.w);
  return u.v;
}

// Packed gate math for a pair of h-rows (proven R6-R9, absmax 3.9e-3).
__device__ __forceinline__ void gates_pair(f32x2 aR, f32x2 aZ, f32x2 aXN,
                                           f32x2 aHN, f32x2& hs) {
  const float K = -1.44269504f;  // -log2(e)
  f32x2 mR = aR * K;
  f32x2 mZ = aZ * K;
  f32x2 ea, eb;
  ea[0] = E2(mR[0]); ea[1] = E2(mR[1]);
  eb[0] = E2(mZ[0]); eb[1] = E2(mZ[1]);
  f32x2 pa = ea + 1.0f;
  f32x2 pb = eb + 1.0f;
  f32x2 prod = pa * pb;
  f32x2 inv;
  inv[0] = __builtin_amdgcn_rcpf(prod[0]);
  inv[1] = __builtin_amdgcn_rcpf(prod[1]);
  f32x2 rg = pb * inv;                 // sigmoid(aR)
  f32x2 zg = pa * inv;                 // sigmoid(aZ)
  f32x2 y = rg * aHN + aXN;
  f32x2 my = y * (2.0f * K);           // -2*log2e*y
  f32x2 c;
  c[0] = E2(my[0]); c[1] = E2(my[1]);
  f32x2 num = 1.0f - c;
  f32x2 den = 1.0f + c;
  f32x2 rin;
  rin[0] = __builtin_amdgcn_rcpf(den[0]);
  rin[1] = __builtin_amdgcn_rcpf(den[1]);
  f32x2 ng = num * rin;                // tanh(y)
  hs = zg * (hs - ng) + ng;
}

// Spin until shared flag >= thr (single-writer flag; read is a broadcast).
__device__ __forceinline__ void waitFlag(volatile int* f, int thr) {
  while (*f < thr) { }
  asm volatile("" ::: "memory");
}

// ============================================================================
// R10: barrier-free GRU.  B=4096, T=128, D=32, H=64.  16 batches / WG,
// WG = 2 waves: wave0 = ALL of layer 0, wave1 = ALL of layer 1.
//
// Row-permutation trick: MFMA output tile T, lane (c,q), reg r holds the gate
// value for ACTUAL row  a(T,q,r) = 32*(T>>1) + 8*q + 4*(T&1) + r.  Then the
// pkrtz-packed pairs [t0r01,t0r23,t1r01,t1r23] form exactly the B-operand
// fragment k = 8q + j (frag0) and [t2..,t3..] form k = 32+8q+j (frag1):
// the C-layout -> B-layout transpose is the IDENTITY in-lane.  Weights /
// biases / fc are loaded with the same row permutation; K-dims stay natural.
// => the whole h-recurrence lives in registers; zero LDS, zero barriers.
//
// A->B handoff: A publishes h0(t) frags (2x ds_write_b128) into an 8-slot
// ring; B ds_reads them (prefetched 1 step ahead).  Sync via two LDS flags
// updated once per 4-step block (A-leads, deadlock-free):
//   A before block k (steps 4k..4k+3, slots mod 8): needs flagB >= 4k-4
//   B before block k: needs flagA >= 4k+4
// ============================================================================
__launch_bounds__(128, 1)
__global__ void gru_fused(const float* __restrict__ x,
                          const float* __restrict__ Wih0, const float* __restrict__ Whh0,
                          const float* __restrict__ bih0, const float* __restrict__ bhh0,
                          const float* __restrict__ Wih1, const float* __restrict__ Whh1,
                          const float* __restrict__ bih1, const float* __restrict__ bhh1,
                          const float* __restrict__ fcw, const float* __restrict__ fcb,
                          float* __restrict__ out) {
  __shared__ f16 RING[8][1024];   // slot t&7: frag0 at [lane*8], frag1 at [512+lane*8]
  __shared__ int flagA;           // steps published by A
  __shared__ int flagB;           // steps consumed by B

  const int tid = threadIdx.x;
  const bool isB = tid >= 64;
  const int lane = tid & 63;
  const int l15 = lane & 15;
  const int q = lane >> 4;
  const int b0 = blockIdx.x * 16;

  if (tid == 0) { flagA = 0; flagB = 0; }

  // ---- register-resident weights (own layer), PERMUTED rows.
  // A-operand row for tile T, lane m=l15: 32*(T>>1) + 8*(m>>2) + 4*(T&1) + (m&3)
  f16x8 wX[3][4][2];   // [gate][tile][kf]  (A uses kf=0 only: K=32)
  f16x8 wH[3][4][2];   // [gate][tile][kf]  K=64
  f32x4 bR[4], bZ[4], bXN[4], bHN[4];
  float fw[4][4];

  const float* WihP = isB ? Wih1 : Wih0;
  const float* WhhP = isB ? Whh1 : Whh0;
  const float* bihP = isB ? bih1 : bih0;
  const float* bhhP = isB ? bhh1 : bhh0;
  const int xstride = isB ? 64 : 32;   // Wih0 is 192x32, Wih1 is 192x64

#pragma unroll
  for (int g = 0; g < 3; ++g) {
#pragma unroll
    for (int T = 0; T < 4; ++T) {
      const int row = g * 64 + 32 * (T >> 1) + 8 * (l15 >> 2) + 4 * (T & 1) + (l15 & 3);
      {
        const float* p = WihP + row * xstride + q * 8;
        wX[g][T][0] = cvt8(*(const float4*)p, *(const float4*)(p + 4));
        if (isB) {
          const float* p1 = p + 32;
          wX[g][T][1] = cvt8(*(const float4*)p1, *(const float4*)(p1 + 4));
        }
      }
#pragma unroll
      for (int kf = 0; kf < 2; ++kf) {
        const float* ph = WhhP + row * 64 + kf * 32 + q * 8;
        wH[g][T][kf] = cvt8(*(const float4*)ph, *(const float4*)(ph + 4));
      }
    }
  }
#pragma unroll
  for (int T = 0; T < 4; ++T)
#pragma unroll
    for (int r = 0; r < 4; ++r) {
      const int o = 32 * (T >> 1) + 8 * q + 4 * (T & 1) + r;   // permuted row index
      bR[T][r] = bihP[o] + bhhP[o];
      bZ[T][r] = bihP[64 + o] + bhhP[64 + o];
      bXN[T][r] = bihP[128 + o];
      bHN[T][r] = bhhP[128 + o];
      fw[T][r] = fcw[o];
    }
  const float fcb0 = fcb[0];

  // h-state (own layer) in C-layout f32 pairs + packed B-frags
  f32x2 hs01[4] = {{0.f,0.f},{0.f,0.f},{0.f,0.f},{0.f,0.f}};
  f32x2 hs23[4] = {{0.f,0.f},{0.f,0.f},{0.f,0.f},{0.f,0.f}};
  f16x8 hf0 = {}, hf1 = {};

  __syncthreads();   // flags + weight loads visible; only barrier in the kernel

  if (!isB) {
    // ==================== wave A: layer 0, steps 0..127 ====================
    const float* xbase = x + (size_t)(b0 + l15) * 4096 + q * 8;
    float4 xa0 = *(const float4*)xbase,        xb0 = *(const float4*)(xbase + 4);
    float4 xa1 = *(const float4*)(xbase + 32), xb1 = *(const float4*)(xbase + 36);

#pragma unroll 1
    for (int tb = 0; tb < 128; tb += 4) {
      if (tb >= 8) waitFlag(&flagB, tb - 4);     // ring backpressure
#pragma unroll
      for (int s = 0; s < 4; ++s) {
        const int t = tb + s;
        const float4 cxa = (s & 1) ? xa1 : xa0;
        const float4 cxb = (s & 1) ? xb1 : xb0;
        if (t + 2 < 128) {
          const float* xp = xbase + (t + 2) * 32;
          if (s & 1) { xa1 = *(const float4*)xp; xb1 = *(const float4*)(xp + 4); }
          else       { xa0 = *(const float4*)xp; xb0 = *(const float4*)(xp + 4); }
        }
        const f16x8 xf = cvt8(cxa, cxb);
#pragma unroll
        for (int T = 0; T < 4; ++T) {
          f32x4 aR  = MFMA16(wX[0][T][0], xf, bR[T]);
          f32x4 aZ  = MFMA16(wX[1][T][0], xf, bZ[T]);
          f32x4 aXN = MFMA16(wX[2][T][0], xf, bXN[T]);
          f32x4 aHN = MFMA16(wH[2][T][0], hf0, bHN[T]);
          aR  = MFMA16(wH[0][T][0], hf0, aR);
          aZ  = MFMA16(wH[1][T][0], hf0, aZ);
          aR  = MFMA16(wH[0][T][1], hf1, aR);
          aZ  = MFMA16(wH[1][T][1], hf1, aZ);
          aHN = MFMA16(wH[2][T][1], hf1, aHN);
          gates_pair(f32x2{aR[0], aR[1]}, f32x2{aZ[0], aZ[1]},
                     f32x2{aXN[0], aXN[1]}, f32x2{aHN[0], aHN[1]}, hs01[T]);
          gates_pair(f32x2{aR[2], aR[3]}, f32x2{aZ[2], aZ[3]},
                     f32x2{aXN[2], aXN[3]}, f32x2{aHN[2], aHN[3]}, hs23[T]);
        }
        // identity transpose: pack C-pairs -> B-frags (k natural order)
        union { h16x2 h2[4]; f16x8 v; } u0, u1;
        u0.h2[0] = __builtin_amdgcn_cvt_pkrtz(hs01[0][0], hs01[0][1]);
        u0.h2[1] = __builtin_amdgcn_cvt_pkrtz(hs23[0][0], hs23[0][1]);
        u0.h2[2] = __builtin_amdgcn_cvt_pkrtz(hs01[1][0], hs01[1][1]);
        u0.h2[3] = __builtin_amdgcn_cvt_pkrtz(hs23[1][0], hs23[1][1]);
        u1.h2[0] = __builtin_amdgcn_cvt_pkrtz(hs01[2][0], hs01[2][1]);
        u1.h2[1] = __builtin_amdgcn_cvt_pkrtz(hs23[2][0], hs23[2][1]);
        u1.h2[2] = __builtin_amdgcn_cvt_pkrtz(hs01[3][0], hs01[3][1]);
        u1.h2[3] = __builtin_amdgcn_cvt_pkrtz(hs23[3][0], hs23[3][1]);
        hf0 = u0.v; hf1 = u1.v;
        f16* slot = &RING[t & 7][0];
        *(f16x8*)&slot[lane * 8] = hf0;
        *(f16x8*)&slot[512 + lane * 8] = hf1;
      }
      LGKM_DRAIN();                              // slot writes landed
      if (lane == 0) *(volatile int*)&flagA = tb + 4;
    }
  } else {
    // ==================== wave B: layer 1, steps 0..127 ====================
    f16x8 gA0, gA1, gB0, gB1;                    // ping-pong h0 frag prefetch
#pragma unroll 1
    for (int tb = 0; tb < 128; tb += 4) {
      waitFlag(&flagA, tb + 4);                  // slots tb..tb+3 ready
      {
        const f16* slot = &RING[tb & 7][0];
        gA0 = *(const f16x8*)&slot[lane * 8];
        gA1 = *(const f16x8*)&slot[512 + lane * 8];
      }
#pragma unroll
      for (int s = 0; s < 4; ++s) {
        const int t = tb + s;
        const f16x8 g0 = (s & 1) ? gB0 : gA0;
        const f16x8 g1 = (s & 1) ? gB1 : gA1;
        if (s < 3) {                             // prefetch next step's frags
          const f16* slot = &RING[(t + 1) & 7][0];
          if (s & 1) { gA0 = *(const f16x8*)&slot[lane * 8]; gA1 = *(const f16x8*)&slot[512 + lane * 8]; }
          else       { gB0 = *(const f16x8*)&slot[lane * 8]; gB1 = *(const f16x8*)&slot[512 + lane * 8]; }
        }
#pragma unroll
        for (int T = 0; T < 4; ++T) {
          f32x4 aR  = MFMA16(wX[0][T][0], g0, bR[T]);
          f32x4 aZ  = MFMA16(wX[1][T][0], g0, bZ[T]);
          f32x4 aXN = MFMA16(wX[2][T][0], g0, bXN[T]);
          f32x4 aHN = MFMA16(wH[2][T][0], hf0, bHN[T]);
          aR  = MFMA16(wX[0][T][1], g1, aR);
          aZ  = MFMA16(wX[1][T][1], g1, aZ);
          aXN = MFMA16(wX[2][T][1], g1, aXN);
          aHN = MFMA16(wH[2][T][1], hf1, aHN);
          aR  = MFMA16(wH[0][T][0], hf0, aR);
          aZ  = MFMA16(wH[1][T][0], hf0, aZ);
          aR  = MFMA16(wH[0][T][1], hf1, aR);
          aZ  = MFMA16(wH[1][T][1], hf1, aZ);
          gates_pair(f32x2{aR[0], aR[1]}, f32x2{aZ[0], aZ[1]},
                     f32x2{aXN[0], aXN[1]}, f32x2{aHN[0], aHN[1]}, hs01[T]);
          gates_pair(f32x2{aR[2], aR[3]}, f32x2{aZ[2], aZ[3]},
                     f32x2{aXN[2], aXN[3]}, f32x2{aHN[2], aHN[3]}, hs23[T]);
        }
        union { h16x2 h2[4]; f16x8 v; } u0, u1;
        u0.h2[0] = __builtin_amdgcn_cvt_pkrtz(hs01[0][0], hs01[0][1]);
        u0.h2[1] = __builtin_amdgcn_cvt_pkrtz(hs23[0][0], hs23[0][1]);
        u0.h2[2] = __builtin_amdgcn_cvt_pkrtz(hs01[1][0], hs01[1][1]);
        u0.h2[3] = __builtin_amdgcn_cvt_pkrtz(hs23[1][0], hs23[1][1]);
        u1.h2[0] = __builtin_amdgcn_cvt_pkrtz(hs01[2][0], hs01[2][1]);
        u1.h2[1] = __builtin_amdgcn_cvt_pkrtz(hs23[2][0], hs23[2][1]);
        u1.h2[2] = __builtin_amdgcn_cvt_pkrtz(hs01[3][0], hs01[3][1]);
        u1.h2[3] = __builtin_amdgcn_cvt_pkrtz(hs23[3][0], hs23[3][1]);
        hf0 = u0.v; hf1 = u1.v;
      }
      LGKM_DRAIN();                              // our slot reads are done
      if (lane == 0) *(volatile int*)&flagB = tb + 4;
    }

    // ---- fc: out[b] = sum_rows fcw_perm[row]*h1[row] + fcb (permutation
    //      cancels in the full dot product since fw uses the same indexing)
    float partial = 0.f;
#pragma unroll
    for (int T = 0; T < 4; ++T)
      partial += fw[T][0] * hs01[T][0] + fw[T][1] * hs01[T][1] +
                 fw[T][2] * hs23[T][0] + fw[T][3] * hs23[T][1];
    partial += __shfl_down(partial, 16, 64);
    partial += __shfl_down(partial, 32, 64);
    if (lane < 16) out[b0 + lane] = partial + fcb0;
  }
}

extern "C" void kernel_launch(void* const* d_in, const int* in_sizes, int n_in,
                              void* d_out, int out_size, void* d_ws, size_t ws_size,
                              hipStream_t stream) {
  (void)in_sizes; (void)n_in; (void)out_size; (void)d_ws; (void)ws_size;
  const float* x    = (const float*)d_in[0];
  const float* Wih0 = (const float*)d_in[1];
  const float* Whh0 = (const float*)d_in[2];
  const float* bih0 = (const float*)d_in[3];
  const float* bhh0 = (const float*)d_in[4];
  const float* Wih1 = (const float*)d_in[5];
  const float* Whh1 = (const float*)d_in[6];
  const float* bih1 = (const float*)d_in[7];
  const float* bhh1 = (const float*)d_in[8];
  const float* fcw  = (const float*)d_in[9];
  const float* fcb  = (const float*)d_in[10];
  float* out = (float*)d_out;

  gru_fused<<<256, 128, 0, stream>>>(x, Wih0, Whh0, bih0, bhh0,
                                     Wih1, Whh1, bih1, bhh1, fcw, fcb, out);
}